// Round 1
// 7408.546 us; speedup vs baseline: 2.3008x; 2.3008x over previous
//
#include <hip/hip_runtime.h>
#include <hip/hip_bf16.h>

// Problem dims
#define S_  128
#define B_  32
#define V_  33278
#define E_  400
#define H_  1150
#define SB_ (S_*B_)        // 4096 rows
#define EP_ 416            // E padded to x32
#define HP_ 1152           // H padded to x32
#define G0_ (4*H_)         // 4600 gates, layers 0/1
#define G2_ (4*E_)         // 1600 gates, layer 2
#define NWG0_ 288          // ceil(1150/4) unit-blocks for layers 0/1
#define NWG2_ 100          // 400/4 unit-blocks for layer 2

typedef __attribute__((ext_vector_type(8))) short short8;   // 8 bf16 (4 VGPRs)
typedef __attribute__((ext_vector_type(4))) float f32x4;

// dst[r][0..Kpad) = bf16(k<K ? src : 0)
__global__ __launch_bounds__(256) void k_castpad(const float* __restrict__ src,
    __hip_bfloat16* __restrict__ dst, int K, int Kpad) {
  int r = blockIdx.y;
  int k = blockIdx.x * 256 + threadIdx.x;
  if (k >= Kpad) return;
  float v = (k < K) ? src[(size_t)r * K + k] : 0.f;
  dst[(size_t)r * Kpad + k] = __float2bfloat16(v);
}

// Masked recurrent weights, bf16 split (w = w1 + w2, w2 = residual), rows
// regrouped per-WG: output row r = wg*16 + gate*4 + ul for unit u = wg*4+ul.
// Row pad (u>=Hh) and col pad (k>=K) are zero -> MFMA-safe.
__global__ __launch_bounds__(256) void k_wsplit(
    const float* __restrict__ w, const float* __restrict__ m,
    __hip_bfloat16* __restrict__ w1, __hip_bfloat16* __restrict__ w2,
    int Hh, int K, int Kpad) {
  int r = blockIdx.y;
  int k = blockIdx.x * 256 + threadIdx.x;
  if (k >= Kpad) return;
  int wg = r >> 4, rl = r & 15;
  int gate = rl >> 2, u = wg * 4 + (rl & 3);
  float v = 0.f;
  if (u < Hh && k < K) {
    size_t idx = (size_t)(gate * Hh + u) * K + k;
    v = w[idx] * m[idx];
  }
  __hip_bfloat16 hi = __float2bfloat16(v);
  w1[(size_t)r * Kpad + k] = hi;
  w2[(size_t)r * Kpad + k] = __float2bfloat16(v - __bfloat162float(hi));
}

__global__ __launch_bounds__(256) void k_zero(int* __restrict__ p, int n) {
  int i = blockIdx.x * 256 + threadIdx.x;
  if (i < n) p[i] = 0;
}

// X[r][0..EP) = bf16(emb[tokens[r]][e]) (zero pad cols)
__global__ __launch_bounds__(64) void k_embed(const int* __restrict__ tok,
    const float* __restrict__ emb, __hip_bfloat16* __restrict__ X) {
  int r = blockIdx.x;
  int t = tok[r];
  const float* er = emb + (size_t)t * E_;
  __hip_bfloat16* xr = X + (size_t)r * EP_;
  for (int e = threadIdx.x; e < EP_; e += 64)
    xr[e] = __float2bfloat16(e < E_ ? er[e] : 0.f);
}

// C[M][N] = A[M][Kpad](bf16) * B[N][Kpad](bf16)^T + bias[N]   (fp32 out)
// 128x128 tile, 4 waves in 2x2, each wave 64x64 via 4x4 mfma_f32_16x16x32_bf16.
__global__ __launch_bounds__(256) void k_gemm_nt(
    const __hip_bfloat16* __restrict__ A, const __hip_bfloat16* __restrict__ Bm,
    const float* __restrict__ bias, float* __restrict__ C,
    int M, int N, int Kpad) {
  __shared__ short As[128][40];   // +8 pad
  __shared__ short Bs[128][40];
  const int tid = threadIdx.x;
  const int m0 = blockIdx.y * 128;
  const int n0 = blockIdx.x * 128;
  const int wv = tid >> 6, ln = tid & 63;
  const int wm = (wv >> 1) * 64, wn = (wv & 1) * 64;
  const int fr = ln & 15, fq = ln >> 4;   // frag row / quad
  const short* Ag = (const short*)A;
  const short* Bg = (const short*)Bm;
  f32x4 acc[4][4] = {};
  for (int k0 = 0; k0 < Kpad; k0 += 32) {
#pragma unroll
    for (int i = 0; i < 2; ++i) {
      int chunk = tid + 256 * i;
      int r = chunk >> 2, q = (chunk & 3) * 8;
      *(short8*)&As[r][q] = *(const short8*)(Ag + (size_t)(m0 + r) * Kpad + k0 + q);
      short8 bv = {};
      if (n0 + r < N) bv = *(const short8*)(Bg + (size_t)(n0 + r) * Kpad + k0 + q);
      *(short8*)&Bs[r][q] = bv;
    }
    __syncthreads();
    short8 af[4], bfr[4];
#pragma unroll
    for (int i = 0; i < 4; ++i) {
      af[i]  = *(const short8*)&As[wm + i * 16 + fr][fq * 8];
      bfr[i] = *(const short8*)&Bs[wn + i * 16 + fr][fq * 8];
    }
#pragma unroll
    for (int i = 0; i < 4; ++i)
#pragma unroll
      for (int j = 0; j < 4; ++j)
        acc[i][j] = __builtin_amdgcn_mfma_f32_16x16x32_bf16(af[i], bfr[j], acc[i][j], 0, 0, 0);
    __syncthreads();
  }
#pragma unroll
  for (int i = 0; i < 4; ++i)
#pragma unroll
    for (int j = 0; j < 4; ++j)
#pragma unroll
      for (int r = 0; r < 4; ++r) {
        int m = m0 + wm + i * 16 + fq * 4 + r;
        int n = n0 + wn + j * 16 + fr;
        if (n < N) C[(size_t)m * N + n] = acc[i][j][r] + bias[n];
      }
}

// One LSTM time step via MFMA, bf16x3 fp32-emulation.
// Grid = nWG unit-blocks (4 units = 16 gate rows each), block = 256 (4 waves):
// wave = (batch-tile tb in {0,1}) x (K-half kh in {0,1}); each wave does a
// 16(rows)x16(batch) tile over its K-half with 3 MFMAs per 32-K step
// (w1*h1 + w1*h2 + w2*h1; w2*h2 ~ 2^-18, dropped). Partials reduced in LDS,
// then 128 threads (4 units x 32 batch) run the gate nonlinearities, update
// c (global, [b][HP]), and write h as bf16 hi/lo pair (double-buffered across
// step launches -> no RAW race) plus X output.
template<int HH, int KP>
__global__ __launch_bounds__(256) void k_rec(
    const float* __restrict__ xp,   // [SB][4*HH] (b_ih already added)
    const __hip_bfloat16* __restrict__ w1, const __hip_bfloat16* __restrict__ w2,
    const float* __restrict__ bhh,  // [4*HH]
    const __hip_bfloat16* __restrict__ h1p, const __hip_bfloat16* __restrict__ h2p,
    __hip_bfloat16* __restrict__ h1n, __hip_bfloat16* __restrict__ h2n,
    float* __restrict__ cT,         // [32][HP_]
    __hip_bfloat16* __restrict__ Xout, // [SB][Wout]
    int Wout, int s, int first) {
  static_assert(KP % 32 == 0, "KP multiple of 32");
  constexpr int NKS  = KP / 32;
  constexpr int NKSH = (NKS + 1) / 2;
  __shared__ float part[4][16][16];
  const int tid = threadIdx.x;
  const int wg  = blockIdx.x;
  if (!first) {
    const int wv = tid >> 6, ln = tid & 63;
    const int fr = ln & 15, fq = ln >> 4;
    const int tb = wv & 1, kh = wv >> 1;
    const short* W1 = (const short*)w1 + (size_t)(wg * 16 + fr) * KP + fq * 8;
    const short* W2 = (const short*)w2 + (size_t)(wg * 16 + fr) * KP + fq * 8;
    const short* B1 = (const short*)h1p + (size_t)(tb * 16 + fr) * KP + fq * 8;
    const short* B2 = (const short*)h2p + (size_t)(tb * 16 + fr) * KP + fq * 8;
    f32x4 ac0 = {}, ac1 = {}, ac2 = {};
#pragma unroll 3
    for (int i = 0; i < NKSH; ++i) {
      int ks = kh * NKSH + i;
      if ((NKS & 1) && ks >= NKS) break;
      int o = ks * 32;
      short8 a1 = *(const short8*)(W1 + o);
      short8 a2 = *(const short8*)(W2 + o);
      short8 b1 = *(const short8*)(B1 + o);
      short8 b2 = *(const short8*)(B2 + o);
      ac0 = __builtin_amdgcn_mfma_f32_16x16x32_bf16(a1, b1, ac0, 0, 0, 0);
      ac1 = __builtin_amdgcn_mfma_f32_16x16x32_bf16(a1, b2, ac1, 0, 0, 0);
      ac2 = __builtin_amdgcn_mfma_f32_16x16x32_bf16(a2, b1, ac2, 0, 0, 0);
    }
    f32x4 acc = ac0 + ac1 + ac2;
#pragma unroll
    for (int r = 0; r < 4; ++r) part[wv][fq * 4 + r][fr] = acc[r];  // D: row=fq*4+r, col=fr
  }
  __syncthreads();
  if (tid < 128) {
    const int b = tid >> 2, ul = tid & 3;     // u fastest -> coalesced xp/h/c access
    const int u = wg * 4 + ul;
    if (u < HH) {
      const size_t row = (size_t)s * 32 + b;
      const float* xr = xp + row * (size_t)(4 * HH);
      float g4[4];
#pragma unroll
      for (int gt = 0; gt < 4; ++gt) {
        float v = xr[gt * HH + u] + bhh[gt * HH + u];
        if (!first) {
          const int c = b & 15, t2 = b >> 4;
          v += part[t2][gt * 4 + ul][c] + part[2 + t2][gt * 4 + ul][c];
        }
        g4[gt] = v;
      }
      float si = 1.f / (1.f + expf(-g4[0]));
      float sf = 1.f / (1.f + expf(-g4[1]));
      float tg = tanhf(g4[2]);
      float so = 1.f / (1.f + expf(-g4[3]));
      float c  = first ? si * tg : fmaf(sf, cT[(size_t)b * HP_ + u], si * tg);
      float h  = so * tanhf(c);
      cT[(size_t)b * HP_ + u] = c;
      __hip_bfloat16 h1 = __float2bfloat16(h);
      h1n[(size_t)b * KP + u] = h1;
      h2n[(size_t)b * KP + u] = __float2bfloat16(h - __bfloat162float(h1));
      Xout[row * Wout + u] = h1;
    }
  }
}

extern "C" void kernel_launch(void* const* d_in, const int* in_sizes, int n_in,
                              void* d_out, int out_size, void* d_ws, size_t ws_size,
                              hipStream_t stream) {
  const int*   tokens = (const int*)  d_in[0];
  const float* emb    = (const float*)d_in[1];
  const float* fc_b   = (const float*)d_in[2];
  const float* w_ih0  = (const float*)d_in[3];
  const float* w_hh0  = (const float*)d_in[4];
  const float* b_ih0  = (const float*)d_in[5];
  const float* b_hh0  = (const float*)d_in[6];
  const float* w_ih1  = (const float*)d_in[7];
  const float* w_hh1  = (const float*)d_in[8];
  const float* b_ih1  = (const float*)d_in[9];
  const float* b_hh1  = (const float*)d_in[10];
  const float* w_ih2  = (const float*)d_in[11];
  const float* w_hh2  = (const float*)d_in[12];
  const float* b_ih2  = (const float*)d_in[13];
  const float* b_hh2  = (const float*)d_in[14];
  const float* mask0  = (const float*)d_in[15];
  const float* mask1  = (const float*)d_in[16];
  const float* mask2  = (const float*)d_in[17];
  float* out = (float*)d_out;

  char* ws = (char*)d_ws;
  size_t off = 0;
  auto alloc = [&](size_t bytes) {
    void* p = ws + off;
    off += (bytes + 255) & ~(size_t)255;
    return p;
  };
  __hip_bfloat16* XA   = (__hip_bfloat16*)alloc((size_t)SB_ * HP_ * 2);
  __hip_bfloat16* XB   = (__hip_bfloat16*)alloc((size_t)SB_ * HP_ * 2);
  float* XP   = (float*)alloc((size_t)SB_ * G0_ * 4);
  float* cT   = (float*)alloc((size_t)HP_ * B_ * 4);
  __hip_bfloat16* w1_0 = (__hip_bfloat16*)alloc((size_t)NWG0_ * 16 * HP_ * 2);
  __hip_bfloat16* w2_0 = (__hip_bfloat16*)alloc((size_t)NWG0_ * 16 * HP_ * 2);
  __hip_bfloat16* w1_1 = (__hip_bfloat16*)alloc((size_t)NWG0_ * 16 * HP_ * 2);
  __hip_bfloat16* w2_1 = (__hip_bfloat16*)alloc((size_t)NWG0_ * 16 * HP_ * 2);
  __hip_bfloat16* w1_2 = (__hip_bfloat16*)alloc((size_t)NWG2_ * 16 * EP_ * 2);
  __hip_bfloat16* w2_2 = (__hip_bfloat16*)alloc((size_t)NWG2_ * 16 * EP_ * 2);
  __hip_bfloat16* hbuf = (__hip_bfloat16*)alloc((size_t)4 * B_ * HP_ * 2);
  __hip_bfloat16* wih0b = (__hip_bfloat16*)alloc((size_t)G0_ * EP_ * 2);
  __hip_bfloat16* wih1b = (__hip_bfloat16*)alloc((size_t)G0_ * HP_ * 2);
  __hip_bfloat16* wih2b = (__hip_bfloat16*)alloc((size_t)G2_ * HP_ * 2);
  __hip_bfloat16* embb  = (__hip_bfloat16*)alloc((size_t)V_ * EP_ * 2);
  if (off > ws_size) return;  // workspace too small: bail (test will fail loudly)

  __hip_bfloat16* h1a = hbuf;
  __hip_bfloat16* h2a = hbuf + (size_t)B_ * HP_;
  __hip_bfloat16* h1b = hbuf + (size_t)2 * B_ * HP_;
  __hip_bfloat16* h2b = hbuf + (size_t)3 * B_ * HP_;

  // Weight prep (every call: masks reapplied, pads zeroed)
  k_wsplit<<<dim3((HP_ + 255) / 256, NWG0_ * 16), 256, 0, stream>>>(w_hh0, mask0, w1_0, w2_0, H_, H_, HP_);
  k_wsplit<<<dim3((HP_ + 255) / 256, NWG0_ * 16), 256, 0, stream>>>(w_hh1, mask1, w1_1, w2_1, H_, H_, HP_);
  k_wsplit<<<dim3((EP_ + 255) / 256, NWG2_ * 16), 256, 0, stream>>>(w_hh2, mask2, w1_2, w2_2, E_, E_, EP_);
  k_castpad<<<dim3((EP_ + 255) / 256, G0_), 256, 0, stream>>>(w_ih0, wih0b, E_, EP_);
  k_castpad<<<dim3((HP_ + 255) / 256, G0_), 256, 0, stream>>>(w_ih1, wih1b, H_, HP_);
  k_castpad<<<dim3((HP_ + 255) / 256, G2_), 256, 0, stream>>>(w_ih2, wih2b, H_, HP_);
  k_castpad<<<dim3((EP_ + 255) / 256, V_),  256, 0, stream>>>(emb,   embb,  E_, EP_);
  k_zero<<<(4 * B_ * HP_ / 2 + 255) / 256, 256, 0, stream>>>((int*)hbuf, 4 * B_ * HP_ / 2);

  // Embedding -> XA [SB][EP] bf16
  k_embed<<<SB_, 64, 0, stream>>>(tokens, emb, XA);

  // Layer 0: xp = XA @ w_ih0^T + b_ih0 ; recurrence -> XB
  k_gemm_nt<<<dim3(36, 32), 256, 0, stream>>>(XA, wih0b, b_ih0, XP, SB_, G0_, EP_);
  for (int s = 0; s < S_; ++s) {
    const __hip_bfloat16 *r1 = (s & 1) ? h1b : h1a, *r2 = (s & 1) ? h2b : h2a;
    __hip_bfloat16 *n1 = (s & 1) ? h1a : h1b, *n2 = (s & 1) ? h2a : h2b;
    k_rec<H_, HP_><<<NWG0_, 256, 0, stream>>>(XP, w1_0, w2_0, b_hh0, r1, r2, n1, n2, cT, XB, HP_, s, s == 0);
  }
  // Layer 1 -> XA
  k_gemm_nt<<<dim3(36, 32), 256, 0, stream>>>(XB, wih1b, b_ih1, XP, SB_, G0_, HP_);
  for (int s = 0; s < S_; ++s) {
    const __hip_bfloat16 *r1 = (s & 1) ? h1b : h1a, *r2 = (s & 1) ? h2b : h2a;
    __hip_bfloat16 *n1 = (s & 1) ? h1a : h1b, *n2 = (s & 1) ? h2a : h2b;
    k_rec<H_, HP_><<<NWG0_, 256, 0, stream>>>(XP, w1_1, w2_1, b_hh1, r1, r2, n1, n2, cT, XA, HP_, s, s == 0);
  }
  // Layer 2 (hidden = E) -> XB  (stride-416 rows of XB; pad cols hit zeroed embb cols)
  k_gemm_nt<<<dim3(13, 32), 256, 0, stream>>>(XA, wih2b, b_ih2, XP, SB_, G2_, HP_);
  for (int s = 0; s < S_; ++s) {
    const __hip_bfloat16 *r1 = (s & 1) ? h1b : h1a, *r2 = (s & 1) ? h2b : h2a;
    __hip_bfloat16 *n1 = (s & 1) ? h1a : h1b, *n2 = (s & 1) ? h2a : h2b;
    k_rec<E_, EP_><<<NWG2_, 256, 0, stream>>>(XP, w1_2, w2_2, b_hh2, r1, r2, n1, n2, cT, XB, EP_, s, s == 0);
  }
  // Output projection: out = XB @ emb^T + fc_bias  [4096][33278] fp32
  k_gemm_nt<<<dim3(260, 32), 256, 0, stream>>>(XB, embb, fc_b, out, SB_, V_, EP_);
}